// Round 1
// baseline (308.871 us; speedup 1.0000x reference)
//
#include <hip/hip_runtime.h>
#include <hip/hip_bf16.h>

#define S_LEN 1024
#define DK 64
#define QB 32
#define NEGV (-1e9f)

typedef __attribute__((ext_vector_type(8))) short bf16x8;
typedef __attribute__((ext_vector_type(16))) float f32x16;

__device__ __forceinline__ unsigned short f2bf(float f) {
    __hip_bfloat16 h = __float2bfloat16(f);
    unsigned short u;
    __builtin_memcpy(&u, &h, 2);
    return u;
}

__device__ __forceinline__ bf16x8 load_cvt8(const float4* p, float scale) {
    float4 a = p[0], b = p[1];
    bf16x8 r;
    r[0] = (short)f2bf(a.x * scale); r[1] = (short)f2bf(a.y * scale);
    r[2] = (short)f2bf(a.z * scale); r[3] = (short)f2bf(a.w * scale);
    r[4] = (short)f2bf(b.x * scale); r[5] = (short)f2bf(b.y * scale);
    r[6] = (short)f2bf(b.z * scale); r[7] = (short)f2bf(b.w * scale);
    return r;
}

__global__ __launch_bounds__(512, 4)
void sdpa_kernel(const float* __restrict__ Q, const float* __restrict__ K,
                 const float* __restrict__ V, const int* __restrict__ M,
                 float* __restrict__ OC, float* __restrict__ OA)
{
    __shared__ float stat[576];
    __shared__ union { unsigned short p[8 * 32 * 128]; float c[8 * 2048]; } big;

    // XCD-aware swizzle: 2048 blocks, each XCD gets 8 contiguous heads.
    const int bid = blockIdx.x;
    const int lin = (bid & 7) * 256 + (bid >> 3);
    const int head = lin >> 5;            // 0..63
    const int q0 = (lin & 31) * QB;       // q-block start

    const int tid = threadIdx.x;
    const int wv = tid >> 6;              // wave 0..7
    const int lo = tid & 31;              // lane & 31
    const int hi = (tid >> 5) & 1;        // lane >> 5

    float* wmax = stat;                   // [8][32]
    float* wsum = stat + 256;             // [8][32]
    float* mrow = stat + 512;             // [32]
    float* invl = stat + 544;             // [32]

    // ---- Q fragments (pre-scaled by 1/sqrt(64)); A layout: row=lane&31, k=8*hi+j
    const float* qptr = Q + (head * S_LEN + q0 + lo) * DK + hi * 8;
    bf16x8 qf[4];
#pragma unroll
    for (int s = 0; s < 4; ++s)
        qf[s] = load_cvt8((const float4*)(qptr + s * 16), 0.125f);

    // ---- QK^T: wave's 32x128 slice as 4 tiles of 32x32, K-loop 4 x K=16
    f32x16 acc[4];
    const float* kbase = K + head * S_LEN * DK;
#pragma unroll
    for (int t = 0; t < 4; ++t) {
        const float* kptr = kbase + (wv * 128 + t * 32 + lo) * DK + hi * 8;
        f32x16 a;
#pragma unroll
        for (int i = 0; i < 16; ++i) a[i] = 0.0f;
#pragma unroll
        for (int s = 0; s < 4; ++s) {
            bf16x8 kf = load_cvt8((const float4*)(kptr + s * 16), 1.0f);
            a = __builtin_amdgcn_mfma_f32_32x32x16_bf16(qf[s], kf, a, 0, 0, 0);
        }
        acc[t] = a;
    }

    // ---- mask: C layout col=lane&31, row=(r&3)+8*(r>>2)+4*hi
    const int* mbase = M + (head * S_LEN + q0) * S_LEN;
#pragma unroll
    for (int t = 0; t < 4; ++t) {
        const int col = wv * 128 + t * 32 + lo;
#pragma unroll
        for (int r = 0; r < 16; ++r) {
            const int row = (r & 3) + 8 * (r >> 2) + 4 * hi;
            int mval = __builtin_nontemporal_load(mbase + row * S_LEN + col);
            if (mval) acc[t][r] = NEGV;
        }
    }

    // ---- row max: per-reg butterfly over 32 cols, then cross-wave via LDS
#pragma unroll
    for (int r = 0; r < 16; ++r) {
        float v = fmaxf(fmaxf(acc[0][r], acc[1][r]), fmaxf(acc[2][r], acc[3][r]));
#pragma unroll
        for (int sh = 16; sh >= 1; sh >>= 1)
            v = fmaxf(v, __shfl_xor(v, sh, 64));
        if (lo == 0) wmax[wv * 32 + ((r & 3) + 8 * (r >> 2) + 4 * hi)] = v;
    }
    __syncthreads();
    if (tid < 32) {
        float m = wmax[tid];
#pragma unroll
        for (int w = 1; w < 8; ++w) m = fmaxf(m, wmax[w * 32 + tid]);
        mrow[tid] = m;
    }
    __syncthreads();

    // ---- exp + row sum (masked entries: exp(-1e9 - m) underflows to 0, matches ref)
#pragma unroll
    for (int r = 0; r < 16; ++r) {
        const int row = (r & 3) + 8 * (r >> 2) + 4 * hi;
        const float m = mrow[row];
        float s0 = __expf(acc[0][r] - m);
        float s1 = __expf(acc[1][r] - m);
        float s2 = __expf(acc[2][r] - m);
        float s3 = __expf(acc[3][r] - m);
        acc[0][r] = s0; acc[1][r] = s1; acc[2][r] = s2; acc[3][r] = s3;
        float v = (s0 + s1) + (s2 + s3);
#pragma unroll
        for (int sh = 16; sh >= 1; sh >>= 1)
            v += __shfl_xor(v, sh, 64);
        if (lo == 0) wsum[wv * 32 + row] = v;
    }
    __syncthreads();
    if (tid < 32) {
        float l = 0.f;
#pragma unroll
        for (int w = 0; w < 8; ++w) l += wsum[w * 32 + tid];
        invl[tid] = 1.0f / l;
    }
    __syncthreads();

    // ---- normalize, write attn (nontemporal), stash bf16 P in swizzled LDS
    float* abase = OA + (head * S_LEN + q0) * S_LEN;
    unsigned short* Pw = big.p + wv * (32 * 128);
#pragma unroll
    for (int t = 0; t < 4; ++t) {
        const int colL = t * 32 + lo;
#pragma unroll
        for (int r = 0; r < 16; ++r) {
            const int row = (r & 3) + 8 * (r >> 2) + 4 * hi;
            float pn = acc[t][r] * invl[row];
            __builtin_nontemporal_store(pn, abase + row * S_LEN + (wv * 128 + colL));
            int off = (row * 256 + colL * 2) ^ ((row & 15) << 4);
            *(unsigned short*)((char*)Pw + off) = f2bf(pn);
        }
    }

    // ---- PV over this wave's 128-k slice (own LDS slice; DS ops in-order per wave)
    f32x16 pv0, pv1;
#pragma unroll
    for (int i = 0; i < 16; ++i) { pv0[i] = 0.f; pv1[i] = 0.f; }
    const float* vbase = V + head * S_LEN * DK;
#pragma unroll
    for (int s = 0; s < 8; ++s) {
        int off = (lo * 256 + s * 32 + hi * 16) ^ ((lo & 15) << 4);
        bf16x8 af = *(const bf16x8*)((const char*)Pw + off);
        const float* vp = vbase + (wv * 128 + s * 16 + hi * 8) * DK;
        bf16x8 v0, v1;
#pragma unroll
        for (int j = 0; j < 8; ++j) {
            v0[j] = (short)f2bf(vp[j * DK + lo]);
            v1[j] = (short)f2bf(vp[j * DK + 32 + lo]);
        }
        pv0 = __builtin_amdgcn_mfma_f32_32x32x16_bf16(af, v0, pv0, 0, 0, 0);
        pv1 = __builtin_amdgcn_mfma_f32_32x32x16_bf16(af, v1, pv1, 0, 0, 0);
    }

    __syncthreads();   // all waves done reading P; reuse LDS as ctx partials
    float* cw = big.c + wv * 2048;
#pragma unroll
    for (int r = 0; r < 16; ++r) {
        const int row = (r & 3) + 8 * (r >> 2) + 4 * hi;
        cw[row * 64 + lo] = pv0[r];
        cw[row * 64 + 32 + lo] = pv1[r];
    }
    __syncthreads();

    // ---- cross-wave reduce (8 partials) + coalesced float4 context store
    const int e = tid * 4;
    float4 s4 = *(const float4*)(big.c + e);
#pragma unroll
    for (int w = 1; w < 8; ++w) {
        float4 t4 = *(const float4*)(big.c + w * 2048 + e);
        s4.x += t4.x; s4.y += t4.y; s4.z += t4.z; s4.w += t4.w;
    }
    const int row = e >> 6, col = e & 63;
    *(float4*)(OC + (head * S_LEN + q0 + row) * DK + col) = s4;
}

extern "C" void kernel_launch(void* const* d_in, const int* in_sizes, int n_in,
                              void* d_out, int out_size, void* d_ws, size_t ws_size,
                              hipStream_t stream) {
    const float* Q = (const float*)d_in[0];
    const float* K = (const float*)d_in[1];
    const float* V = (const float*)d_in[2];
    const int*   M = (const int*)d_in[3];
    float* OC = (float*)d_out;                       // context: 4*16*1024*64
    float* OA = OC + 4 * 16 * 1024 * 64;             // attn:    4*16*1024*1024
    sdpa_kernel<<<dim3(2048), dim3(512), 0, stream>>>(Q, K, V, M, OC, OA);
}